// Round 8
// baseline (1510.669 us; speedup 1.0000x reference)
//
#include <hip/hip_runtime.h>

// SNN policy, dense-MFMA edition (round 13: occupancy 3->5 blocks/CU).
// Block = 4 waves = 16 batch elements (M=16). Wave w owns neuron slice
// [32w, 32w+32). Weights as EXACT-ish 2-way round-to-nearest bf16 splits
// (w = hi + mid + resid, |resid| <= 2^-18 |w|): spike GEMMs on MFMA.
// BOTH w_rec splits in registers. z spikes: 16x128 bf16 LDS tile
// (swizzled, double-buffered), written in C-frag layout, read as A-frags.
//
// r12 post-mortem: stall-bound, ~3371 cy step latency vs ~790 cy/wave of
// issue; 3 resident waves/SIMD leave ~30% holes. ILP moves (r9, r12)
// were flat; resident-wave count is the scarce resource. r11 runs at
// VGPR=80 yet launch_bounds(256,3) has pinned occupancy at 3 blocks/CU
// since round 5. This round:
//   1. __launch_bounds__(256,5): VGPR cap 102 (22-reg headroom over 80,
//      far from the r8/r10 spill cliff) -> up to 5 blocks/CU.
//   2. crec chain seeded with cin (acc = cin -> crM x4 -> crH x4;
//      iS = id + acc): kills one zero-init + merge adds per t.
//      Reorder-class change; r8/r9/r11 reorders all kept absmax exact.
// Guard counter: WRITE_SIZE == 512 KB (any more = rolling spill = revert).

#pragma clang fp contract(off)

typedef float f32x4 __attribute__((ext_vector_type(4)));
typedef float f32x2 __attribute__((ext_vector_type(2)));
typedef short short8 __attribute__((ext_vector_type(8)));
typedef int int4v __attribute__((ext_vector_type(4)));

constexpr int TSTEPS = 40;

// round-to-nearest-even bf16, returned as f32 bit pattern (low 16 zero)
__device__ __forceinline__ unsigned rnbf(float f) {
    unsigned u = __float_as_uint(f);
    return (u + 0x7FFFu + ((u >> 16) & 1u)) & 0xFFFF0000u;
}

// 2-way RN split of an f32 pair into packed bf16 (lo16 = even-k element)
__device__ __forceinline__ void split2pair(float a, float b,
                                           unsigned& hi, unsigned& mi) {
    unsigned ha = rnbf(a), hb = rnbf(b);
    float ra = a - __uint_as_float(ha);
    float rb = b - __uint_as_float(hb);
    unsigned ma = rnbf(ra), mb = rnbf(rb);
    hi = (ha >> 16) | (hb & 0xFFFF0000u);
    mi = (ma >> 16) | (mb & 0xFFFF0000u);
}

__device__ __forceinline__ f32x4 mfma16(int4v a, int4v b, f32x4 c) {
    return __builtin_amdgcn_mfma_f32_16x16x32_bf16(
        __builtin_bit_cast(short8, a), __builtin_bit_cast(short8, b), c, 0, 0, 0);
}

template <int CTRL>
__device__ __forceinline__ float dpp_mov(float v) {
    return __int_as_float(
        __builtin_amdgcn_update_dpp(0, __float_as_int(v), CTRL, 0xF, 0xF, true));
}

__device__ __forceinline__ f32x2 lo2(f32x4 a) {
    return __builtin_shufflevector(a, a, 0, 1);
}
__device__ __forceinline__ f32x2 hi2(f32x4 a) {
    return __builtin_shufflevector(a, a, 2, 3);
}

__global__ __launch_bounds__(256, 5) void snn_kernel(
    const float* __restrict__ x,
    const float* __restrict__ w_in,
    const float* __restrict__ w_rec,
    const float* __restrict__ w_out,
    float* __restrict__ out)
{
    __shared__ char zraw[8192];     // 2 x (16 rows x 128 cols bf16), swizzled

    const int tid = threadIdx.x;
    const int l   = tid & 63;
    const int wv  = tid >> 6;      // wave 0..3
    const int cl  = l & 15;        // row (A/write col-lane) / col (B/C)
    const int kg  = l >> 4;        // k-group 0..3
    const int kb  = kg * 8;        // k base within a 32-chunk
    const int b0  = blockIdx.x * 16;
    const int Ns  = wv * 32;       // neuron slice base

    // packed-op constants
    const f32x2 P1  = {0.1f, 0.1f};
    const f32x2 P02 = {0.2f, 0.2f};

    // ---- recurrent weights: BOTH splits -> registers
    int4v BrecHi[2][4], BrecMi[2][4];
#pragma unroll
    for (int t = 0; t < 2; ++t) {
        int n = Ns + t * 16 + cl;
#pragma unroll
        for (int kc = 0; kc < 4; ++kc) {
            const float* wp = w_rec + n * 128 + kc * 32 + kb;
            float4 wa = *reinterpret_cast<const float4*>(wp);
            float4 wb = *reinterpret_cast<const float4*>(wp + 4);
            float w8[8] = {wa.x, wa.y, wa.z, wa.w, wb.x, wb.y, wb.z, wb.w};
#pragma unroll
            for (int r = 0; r < 4; ++r) {
                unsigned h, m;
                split2pair(w8[2 * r], w8[2 * r + 1], h, m);
                BrecHi[t][kc][r] = (int)h;
                BrecMi[t][kc][r] = (int)m;
            }
        }
    }

    // ---- input weights, hi+mid PACKED in one B-frag (kg0=hi, kg1=mid)
    int4v BwinPk[2];
#pragma unroll
    for (int t = 0; t < 2; ++t) {
        int n = Ns + t * 16 + cl;
        float w8[8];
#pragma unroll
        for (int j = 0; j < 8; ++j)
            w8[j] = (kg < 2) ? w_in[n * 8 + j] : 0.0f;
#pragma unroll
        for (int r = 0; r < 4; ++r) {
            unsigned h, m;
            split2pair(w8[2 * r], w8[2 * r + 1], h, m);
            BwinPk[t][r] = (int)(kg == 0 ? h : (kg == 1 ? m : 0u));
        }
    }

    // ---- readout weights: cols 0,1 = hi(ch0),hi(ch1); cols 2,3 = mid
    int4v Bwout[4];
    {
        int  ch   = cl & 1;
        int  part = (cl >> 1) & 1;
        bool act  = cl < 4;
#pragma unroll
        for (int kc = 0; kc < 4; ++kc) {
            float w8[8];
#pragma unroll
            for (int j = 0; j < 8; ++j)
                w8[j] = act ? w_out[ch * 128 + kc * 32 + kb + j] : 0.0f;
#pragma unroll
            for (int r = 0; r < 4; ++r) {
                unsigned h, m;
                split2pair(w8[2 * r], w8[2 * r + 1], h, m);
                Bwout[kc][r] = (int)(part ? m : h);
            }
        }
    }

    // ---- encoder: lane handles (elem = l>>3, ch = l&7) and (elem+8, same ch)
    float xv0 = x[(size_t)(b0 + (l >> 3)) * 4 + (l & 3)];
    float xv1 = x[(size_t)(b0 + 8 + (l >> 3)) * 4 + (l & 3)];
    float s0 = 50.0f * xv0, s1 = 50.0f * xv1;
    f32x2 cur;
    cur[0] = (l & 4) ? fmaxf(-s0, 0.0f) : fmaxf(s0, 0.0f);
    cur[1] = (l & 4) ? fmaxf(-s1, 0.0f) : fmaxf(s1, 0.0f);
    f32x2 ve = {0.0f, 0.0f};

    // ---- states (C-frag layout: col=lane&15, row=(lane>>4)*4+reg)
    f32x2 iSl[2] = {{0,0},{0,0}}, iSh[2] = {{0,0},{0,0}};
    f32x2 vSl[2] = {{0,0},{0,0}}, vSh[2] = {{0,0},{0,0}};
    f32x2 io_l = {0,0}, io_h = {0,0}, vo_l = {0,0}, vo_h = {0,0};
    f32x4 mx = {-3e38f,-3e38f,-3e38f,-3e38f};

    // ---- z-tile LDS addresses (byte ^ ((row&7)<<4) swizzle; bit12 = buffer)
    // write addr(t,r) = (awrb[t] ^ (r<<4)) + r*256   [r compile-time]
    unsigned awrb[2];
#pragma unroll
    for (int t = 0; t < 2; ++t) {
        int col = Ns + t * 16 + cl;
        awrb[t] = (unsigned)((kg * 1024 + col * 2) ^ ((kg & 1) << 6));
    }
    unsigned ard = (unsigned)((cl * 256 + kg * 16) ^ ((cl & 7) << 4)) | 4096u;

    auto loadfrags = [&](int4v* zf) {
#pragma unroll
        for (int kc = 0; kc < 4; ++kc)
            zf[kc] = *reinterpret_cast<int4v*>(&zraw[ard ^ (unsigned)(kc << 6)]);
    };

    auto readout = [&](const int4v* zf) {
        f32x4 cro = {0,0,0,0};
#pragma unroll
        for (int kc = 0; kc < 4; ++kc) cro = mfma16(zf[kc], Bwout[kc], cro);
        f32x4 cr;
#pragma unroll
        for (int r = 0; r < 4; ++r) cr[r] = cro[r] + dpp_mov<0x4E>(cro[r]);
        // von = vo + 0.1*((0 - vo) + io); (0-vo)+io == io - vo (one rounding)
        f32x2 t2l = io_l - vo_l;
        f32x2 t2h = io_h - vo_h;
        f32x2 vnl = vo_l + P1 * t2l;
        f32x2 vnh = vo_h + P1 * t2h;
        // io = (io - 0.2*io) + cr   (vo used OLD io above)
        io_l = (io_l - P02 * io_l) + lo2(cr);
        io_h = (io_h - P02 * io_h) + hi2(cr);
        vo_l = vnl;
        vo_h = vnh;
        mx[0] = fmaxf(mx[0], vnl[0]);
        mx[1] = fmaxf(mx[1], vnl[1]);
        mx[2] = fmaxf(mx[2], vnh[0]);
        mx[3] = fmaxf(mx[3], vnh[1]);
    };

    auto encoder_lif = [&](bool with_rec, const int4v* zf) {
        // encoder (np chain; (0-ve)+cur == cur-ve, one rounding)
        f32x2 te = cur - ve;
        f32x2 vv = ve + P1 * te;
        bool e0 = vv[0] > 1.0f, e1 = vv[1] > 1.0f;
        unsigned long long bm0 = __ballot(e0), bm1 = __ballot(e1);
        ve[0] = e0 ? 0.0f : vv[0];
        ve[1] = e1 ? 0.0f : vv[1];
        // xt A-frag from ballot bytes; lanes 0-31 carry the byte (k 0-7 for
        // the hi half of BwinPk, duplicated k 8-15 for the mid half)
        unsigned long long src = (cl < 8) ? (bm0 >> (cl * 8)) : (bm1 >> ((cl - 8) * 8));
        unsigned byt = (l < 32) ? ((unsigned)src & 0xFFu) : 0u;
        int4v axt;
        axt[0] = (int)(((byt & 1u)   ? 0x3F80u : 0u) | ((byt & 2u)   ? 0x3F800000u : 0u));
        axt[1] = (int)(((byt & 4u)   ? 0x3F80u : 0u) | ((byt & 8u)   ? 0x3F800000u : 0u));
        axt[2] = (int)(((byt & 16u)  ? 0x3F80u : 0u) | ((byt & 32u)  ? 0x3F800000u : 0u));
        axt[3] = (int)(((byt & 64u)  ? 0x3F80u : 0u) | ((byt & 128u) ? 0x3F800000u : 0u));
#pragma unroll
        for (int t = 0; t < 2; ++t) {
            // seeded chain: acc = cin -> crM x4 -> crH x4 (one accumulator)
            f32x4 acc = {0,0,0,0};
            acc = mfma16(axt, BwinPk[t], acc);   // cin (hi + mid in one pass)
            if (with_rec) {
#pragma unroll
                for (int kc = 0; kc < 4; ++kc)
                    acc = mfma16(zf[kc], BrecMi[t][kc], acc);
#pragma unroll
                for (int kc = 0; kc < 4; ++kc)
                    acc = mfma16(zf[kc], BrecHi[t][kc], acc);
            }
            // id = i - 0.2*i ; tt = (0-v)+i == i-v ; vd = v + 0.1*tt
            f32x2 idl = iSl[t] - P02 * iSl[t];
            f32x2 idh = iSh[t] - P02 * iSh[t];
            f32x2 ttl = iSl[t] - vSl[t];
            f32x2 tth = iSh[t] - vSh[t];
            f32x2 vdl = vSl[t] + P1 * ttl;
            f32x2 vdh = vSh[t] + P1 * tth;
#pragma unroll
            for (int r = 0; r < 4; ++r) {
                float vdr = (r < 2) ? vdl[r] : vdh[r - 2];
                bool zb = vdr > 1.0f;
                float vres = zb ? 0.0f : vdr;
                if (r == 0)      vSl[t][0] = vres;
                else if (r == 1) vSl[t][1] = vres;
                else if (r == 2) vSh[t][0] = vres;
                else             vSh[t][1] = vres;
                short zv = zb ? (short)0x3F80 : (short)0;
                unsigned a = (awrb[t] ^ (unsigned)(r << 4)) + (unsigned)(r * 256);
                *reinterpret_cast<short*>(&zraw[a]) = zv;
            }
            // iS = id + acc
            iSl[t] = idl + lo2(acc);
            iSh[t] = idh + hi2(acc);
        }
    };

    auto toggle = [&]() {
        ard ^= 4096u;
        awrb[0] ^= 4096u;
        awrb[1] ^= 4096u;
    };

    // ---- u = 0: no recurrent, no readout (z(-1)=0); writes z(0) -> buf0
    encoder_lif(false, nullptr);
    __syncthreads();
    toggle();

#pragma unroll 1
    for (int u = 1; u < TSTEPS; ++u) {
        int4v zf[4];
        loadfrags(zf);          // z(u-1)
        readout(zf);            // vo(u-1), io(u-1)
        encoder_lif(true, zf);  // i/v/z(u)
        __syncthreads();
        toggle();
    }

    // ---- epilogue: vo(39) from z(39)
    {
        int4v zf[4];
        loadfrags(zf);
        readout(zf);
    }

    // ---- softmax over (mx[.][ch0], mx[.][ch1]) and store
#pragma unroll
    for (int r = 0; r < 4; ++r) {
        float partner = dpp_mov<0xB1>(mx[r]);
        float mm = fmaxf(mx[r], partner);
        float es = expf(mx[r] - mm);
        float ep = expf(partner - mm);
        float inv = 1.0f / (es + ep);
        float pr = es * inv;
        if (cl < 2) out[(size_t)(b0 + kg * 4 + r) * 2 + cl] = pr;
    }
}

extern "C" void kernel_launch(void* const* d_in, const int* in_sizes, int n_in,
                              void* d_out, int out_size, void* d_ws, size_t ws_size,
                              hipStream_t stream) {
    const float* x     = (const float*)d_in[0];
    const float* w_in  = (const float*)d_in[1];
    const float* w_rec = (const float*)d_in[2];
    const float* w_out = (const float*)d_in[3];
    float* out = (float*)d_out;

    int B = in_sizes[0] / 4;      // x is (B, 4)
    int blocks = B / 16;          // 16 batch elements per 256-thread block
    snn_kernel<<<blocks, 256, 0, stream>>>(x, w_in, w_rec, w_out, out);
}

// Round 9
// 313.355 us; speedup vs baseline: 4.8210x; 4.8210x over previous
//
#include <hip/hip_runtime.h>

// SNN policy, dense-MFMA edition (round 14: 4 blocks/CU via hybrid weights).
// Block = 4 waves = 16 batch elements (M=16). Wave w owns neuron slice
// [32w, 32w+32). Weights as EXACT-ish 2-way round-to-nearest bf16 splits
// (w = hi + mid + resid, |resid| <= 2^-18 |w|): spike GEMMs on MFMA.
// hi split of w_rec in registers; mid split in XOR-swizzled LDS.
// z spikes: 16x128 bf16 LDS tile (swizzled, double-buffered).
//
// Register-budget law learned from r8/r10/r13 spills: per-wave budget
// (512/waves) must hold ARCH + AGPR together; weights-in-AGPR are
// invisible in VGPR_Count. (256,3)=170: 80+88 fits. (256,4)=128: needs
// weights <= ~56 -> BrecMi (32 regs) moves to LDS (r7's proven layout).
//   arch ~70 (states 28, zf 16, cur/ve 4, addr 6, consts 4, transients)
//   + acc 56 (BrecHi 32, BwinPk 8, Bwout 16) = ~126 <= 128.
// LDS 8KB z + 32KB mid = 40KB x 4 blocks = 160KB = full CU capacity.
// Occupancy 3->4 waves/SIMD (+33% latency hiding) vs +125cy/step of
// re-added mid-read conflicts -- the trade the stall model says to make.
// Numerics: values and op order IDENTICAL to r11 (absmax 0.001953125).
// Guard counter: WRITE_SIZE == 512 KB (any more = spill = revert to r11).

#pragma clang fp contract(off)

typedef float f32x4 __attribute__((ext_vector_type(4)));
typedef float f32x2 __attribute__((ext_vector_type(2)));
typedef short short8 __attribute__((ext_vector_type(8)));
typedef int int4v __attribute__((ext_vector_type(4)));

constexpr int TSTEPS = 40;

// round-to-nearest-even bf16, returned as f32 bit pattern (low 16 zero)
__device__ __forceinline__ unsigned rnbf(float f) {
    unsigned u = __float_as_uint(f);
    return (u + 0x7FFFu + ((u >> 16) & 1u)) & 0xFFFF0000u;
}

// 2-way RN split of an f32 pair into packed bf16 (lo16 = even-k element)
__device__ __forceinline__ void split2pair(float a, float b,
                                           unsigned& hi, unsigned& mi) {
    unsigned ha = rnbf(a), hb = rnbf(b);
    float ra = a - __uint_as_float(ha);
    float rb = b - __uint_as_float(hb);
    unsigned ma = rnbf(ra), mb = rnbf(rb);
    hi = (ha >> 16) | (hb & 0xFFFF0000u);
    mi = (ma >> 16) | (mb & 0xFFFF0000u);
}

__device__ __forceinline__ f32x4 mfma16(int4v a, int4v b, f32x4 c) {
    return __builtin_amdgcn_mfma_f32_16x16x32_bf16(
        __builtin_bit_cast(short8, a), __builtin_bit_cast(short8, b), c, 0, 0, 0);
}

template <int CTRL>
__device__ __forceinline__ float dpp_mov(float v) {
    return __int_as_float(
        __builtin_amdgcn_update_dpp(0, __float_as_int(v), CTRL, 0xF, 0xF, true));
}

__device__ __forceinline__ f32x2 lo2(f32x4 a) {
    return __builtin_shufflevector(a, a, 0, 1);
}
__device__ __forceinline__ f32x2 hi2(f32x4 a) {
    return __builtin_shufflevector(a, a, 2, 3);
}

__global__ __launch_bounds__(256, 4) void snn_kernel(
    const float* __restrict__ x,
    const float* __restrict__ w_in,
    const float* __restrict__ w_rec,
    const float* __restrict__ w_out,
    float* __restrict__ out)
{
    __shared__ char zraw[8192];     // 2 x (16 rows x 128 cols bf16), swizzled
    __shared__ char midraw[32768];  // w_rec mid split as B-frags, swizzled

    const int tid = threadIdx.x;
    const int l   = tid & 63;
    const int wv  = tid >> 6;      // wave 0..3
    const int cl  = l & 15;        // row (A/write col-lane) / col (B/C)
    const int kg  = l >> 4;        // k-group 0..3
    const int kb  = kg * 8;        // k base within a 32-chunk
    const int b0  = blockIdx.x * 16;
    const int Ns  = wv * 32;       // neuron slice base

    // packed-op constants
    const f32x2 P1  = {0.1f, 0.1f};
    const f32x2 P02 = {0.2f, 0.2f};

    // ---- recurrent weights: hi split -> regs, mid split -> swizzled LDS
    int4v BrecHi[2][4];
    unsigned amid[2];              // per-tile LDS base (n*256 + kg*16), swz
    unsigned aswz[2];
#pragma unroll
    for (int t = 0; t < 2; ++t) {
        int n = Ns + t * 16 + cl;
        amid[t] = (unsigned)(n * 256 + kg * 16);
        aswz[t] = (unsigned)((n & 7) << 4);
#pragma unroll
        for (int kc = 0; kc < 4; ++kc) {
            const float* wp = w_rec + n * 128 + kc * 32 + kb;
            float4 wa = *reinterpret_cast<const float4*>(wp);
            float4 wb = *reinterpret_cast<const float4*>(wp + 4);
            float w8[8] = {wa.x, wa.y, wa.z, wa.w, wb.x, wb.y, wb.z, wb.w};
            int4v mfrag;
#pragma unroll
            for (int r = 0; r < 4; ++r) {
                unsigned h, m;
                split2pair(w8[2 * r], w8[2 * r + 1], h, m);
                BrecHi[t][kc][r] = (int)h;
                mfrag[r] = (int)m;
            }
            *reinterpret_cast<int4v*>(
                &midraw[(amid[t] + kc * 64) ^ aswz[t]]) = mfrag;
        }
    }

    // ---- input weights, hi+mid PACKED in one B-frag (kg0=hi, kg1=mid)
    int4v BwinPk[2];
#pragma unroll
    for (int t = 0; t < 2; ++t) {
        int n = Ns + t * 16 + cl;
        float w8[8];
#pragma unroll
        for (int j = 0; j < 8; ++j)
            w8[j] = (kg < 2) ? w_in[n * 8 + j] : 0.0f;
#pragma unroll
        for (int r = 0; r < 4; ++r) {
            unsigned h, m;
            split2pair(w8[2 * r], w8[2 * r + 1], h, m);
            BwinPk[t][r] = (int)(kg == 0 ? h : (kg == 1 ? m : 0u));
        }
    }

    // ---- readout weights: cols 0,1 = hi(ch0),hi(ch1); cols 2,3 = mid
    int4v Bwout[4];
    {
        int  ch   = cl & 1;
        int  part = (cl >> 1) & 1;
        bool act  = cl < 4;
#pragma unroll
        for (int kc = 0; kc < 4; ++kc) {
            float w8[8];
#pragma unroll
            for (int j = 0; j < 8; ++j)
                w8[j] = act ? w_out[ch * 128 + kc * 32 + kb + j] : 0.0f;
#pragma unroll
            for (int r = 0; r < 4; ++r) {
                unsigned h, m;
                split2pair(w8[2 * r], w8[2 * r + 1], h, m);
                Bwout[kc][r] = (int)(part ? m : h);
            }
        }
    }

    // ---- encoder: lane handles (elem = l>>3, ch = l&7) and (elem+8, same ch)
    float xv0 = x[(size_t)(b0 + (l >> 3)) * 4 + (l & 3)];
    float xv1 = x[(size_t)(b0 + 8 + (l >> 3)) * 4 + (l & 3)];
    float s0 = 50.0f * xv0, s1 = 50.0f * xv1;
    f32x2 cur;
    cur[0] = (l & 4) ? fmaxf(-s0, 0.0f) : fmaxf(s0, 0.0f);
    cur[1] = (l & 4) ? fmaxf(-s1, 0.0f) : fmaxf(s1, 0.0f);
    f32x2 ve = {0.0f, 0.0f};

    // ---- states (C-frag layout: col=lane&15, row=(lane>>4)*4+reg)
    f32x2 iSl[2] = {{0,0},{0,0}}, iSh[2] = {{0,0},{0,0}};
    f32x2 vSl[2] = {{0,0},{0,0}}, vSh[2] = {{0,0},{0,0}};
    f32x2 io_l = {0,0}, io_h = {0,0}, vo_l = {0,0}, vo_h = {0,0};
    f32x4 mx = {-3e38f,-3e38f,-3e38f,-3e38f};

    // ---- z-tile LDS addresses (byte ^ ((row&7)<<4) swizzle; bit12 = buffer)
    // write addr(t,r) = (awrb[t] ^ (r<<4)) + r*256   [r compile-time]
    unsigned awrb[2];
#pragma unroll
    for (int t = 0; t < 2; ++t) {
        int col = Ns + t * 16 + cl;
        awrb[t] = (unsigned)((kg * 1024 + col * 2) ^ ((kg & 1) << 6));
    }
    unsigned ard = (unsigned)((cl * 256 + kg * 16) ^ ((cl & 7) << 4)) | 4096u;

    auto loadfrags = [&](int4v* zf) {
#pragma unroll
        for (int kc = 0; kc < 4; ++kc)
            zf[kc] = *reinterpret_cast<int4v*>(&zraw[ard ^ (unsigned)(kc << 6)]);
    };

    auto readout = [&](const int4v* zf) {
        f32x4 cro = {0,0,0,0};
#pragma unroll
        for (int kc = 0; kc < 4; ++kc) cro = mfma16(zf[kc], Bwout[kc], cro);
        f32x4 cr;
#pragma unroll
        for (int r = 0; r < 4; ++r) cr[r] = cro[r] + dpp_mov<0x4E>(cro[r]);
        // von = vo + 0.1*((0 - vo) + io); (0-vo)+io == io - vo (one rounding)
        f32x2 t2l = io_l - vo_l;
        f32x2 t2h = io_h - vo_h;
        f32x2 vnl = vo_l + P1 * t2l;
        f32x2 vnh = vo_h + P1 * t2h;
        // io = (io - 0.2*io) + cr   (vo used OLD io above)
        io_l = (io_l - P02 * io_l) + lo2(cr);
        io_h = (io_h - P02 * io_h) + hi2(cr);
        vo_l = vnl;
        vo_h = vnh;
        mx[0] = fmaxf(mx[0], vnl[0]);
        mx[1] = fmaxf(mx[1], vnl[1]);
        mx[2] = fmaxf(mx[2], vnh[0]);
        mx[3] = fmaxf(mx[3], vnh[1]);
    };

    auto encoder_lif = [&](bool with_rec, const int4v* zf) {
        // encoder (np chain; (0-ve)+cur == cur-ve, one rounding)
        f32x2 te = cur - ve;
        f32x2 vv = ve + P1 * te;
        bool e0 = vv[0] > 1.0f, e1 = vv[1] > 1.0f;
        unsigned long long bm0 = __ballot(e0), bm1 = __ballot(e1);
        ve[0] = e0 ? 0.0f : vv[0];
        ve[1] = e1 ? 0.0f : vv[1];
        // xt A-frag from ballot bytes; lanes 0-31 carry the byte (k 0-7 for
        // the hi half of BwinPk, duplicated k 8-15 for the mid half)
        unsigned long long src = (cl < 8) ? (bm0 >> (cl * 8)) : (bm1 >> ((cl - 8) * 8));
        unsigned byt = (l < 32) ? ((unsigned)src & 0xFFu) : 0u;
        int4v axt;
        axt[0] = (int)(((byt & 1u)   ? 0x3F80u : 0u) | ((byt & 2u)   ? 0x3F800000u : 0u));
        axt[1] = (int)(((byt & 4u)   ? 0x3F80u : 0u) | ((byt & 8u)   ? 0x3F800000u : 0u));
        axt[2] = (int)(((byt & 16u)  ? 0x3F80u : 0u) | ((byt & 32u)  ? 0x3F800000u : 0u));
        axt[3] = (int)(((byt & 64u)  ? 0x3F80u : 0u) | ((byt & 128u) ? 0x3F800000u : 0u));
#pragma unroll
        for (int t = 0; t < 2; ++t) {
            f32x4 cin = {0,0,0,0};
            cin = mfma16(axt, BwinPk[t], cin);   // hi + mid in one pass
            f32x4 crec = {0,0,0,0};
            if (with_rec) {
                int4v bm[4];
#pragma unroll
                for (int kc = 0; kc < 4; ++kc)
                    bm[kc] = *reinterpret_cast<int4v*>(
                        &midraw[(amid[t] + kc * 64) ^ aswz[t]]);
#pragma unroll
                for (int kc = 0; kc < 4; ++kc)
                    crec = mfma16(zf[kc], bm[kc], crec);
#pragma unroll
                for (int kc = 0; kc < 4; ++kc)
                    crec = mfma16(zf[kc], BrecHi[t][kc], crec);
            }
            // id = i - 0.2*i ; tt = (0-v)+i == i-v ; vd = v + 0.1*tt
            f32x2 idl = iSl[t] - P02 * iSl[t];
            f32x2 idh = iSh[t] - P02 * iSh[t];
            f32x2 ttl = iSl[t] - vSl[t];
            f32x2 tth = iSh[t] - vSh[t];
            f32x2 vdl = vSl[t] + P1 * ttl;
            f32x2 vdh = vSh[t] + P1 * tth;
#pragma unroll
            for (int r = 0; r < 4; ++r) {
                float vdr = (r < 2) ? vdl[r] : vdh[r - 2];
                bool zb = vdr > 1.0f;
                float vres = zb ? 0.0f : vdr;
                if (r == 0)      vSl[t][0] = vres;
                else if (r == 1) vSl[t][1] = vres;
                else if (r == 2) vSh[t][0] = vres;
                else             vSh[t][1] = vres;
                short zv = zb ? (short)0x3F80 : (short)0;
                unsigned a = (awrb[t] ^ (unsigned)(r << 4)) + (unsigned)(r * 256);
                *reinterpret_cast<short*>(&zraw[a]) = zv;
            }
            // iS = (id + cin) + crec    [r11 order]
            iSl[t] = (idl + lo2(cin)) + lo2(crec);
            iSh[t] = (idh + hi2(cin)) + hi2(crec);
        }
    };

    auto toggle = [&]() {
        ard ^= 4096u;
        awrb[0] ^= 4096u;
        awrb[1] ^= 4096u;
    };

    // ---- u = 0: no recurrent, no readout (z(-1)=0); writes z(0) -> buf0
    // (also publishes midraw via the same barrier)
    encoder_lif(false, nullptr);
    __syncthreads();
    toggle();

#pragma unroll 1
    for (int u = 1; u < TSTEPS; ++u) {
        int4v zf[4];
        loadfrags(zf);          // z(u-1)
        readout(zf);            // vo(u-1), io(u-1)
        encoder_lif(true, zf);  // i/v/z(u)
        __syncthreads();
        toggle();
    }

    // ---- epilogue: vo(39) from z(39)
    {
        int4v zf[4];
        loadfrags(zf);
        readout(zf);
    }

    // ---- softmax over (mx[.][ch0], mx[.][ch1]) and store
#pragma unroll
    for (int r = 0; r < 4; ++r) {
        float partner = dpp_mov<0xB1>(mx[r]);
        float mm = fmaxf(mx[r], partner);
        float es = expf(mx[r] - mm);
        float ep = expf(partner - mm);
        float inv = 1.0f / (es + ep);
        float pr = es * inv;
        if (cl < 2) out[(size_t)(b0 + kg * 4 + r) * 2 + cl] = pr;
    }
}

extern "C" void kernel_launch(void* const* d_in, const int* in_sizes, int n_in,
                              void* d_out, int out_size, void* d_ws, size_t ws_size,
                              hipStream_t stream) {
    const float* x     = (const float*)d_in[0];
    const float* w_in  = (const float*)d_in[1];
    const float* w_rec = (const float*)d_in[2];
    const float* w_out = (const float*)d_in[3];
    float* out = (float*)d_out;

    int B = in_sizes[0] / 4;      // x is (B, 4)
    int blocks = B / 16;          // 16 batch elements per 256-thread block
    snn_kernel<<<blocks, 256, 0, stream>>>(x, w_in, w_rec, w_out, out);
}

// Round 10
// 245.409 us; speedup vs baseline: 6.1557x; 1.2769x over previous
//
#include <hip/hip_runtime.h>

// SNN policy, dense-MFMA edition (round 15: dedup cross-wave-identical work).
// Base = round 11 (299.5us): 4 waves, 16 batch, both w_rec splits in regs,
// (256,3), z via swizzled LDS. Occupancy route is closed (4 spill rounds:
// allocator halves the budget arch/AGPR; arch ~70-80 only fits at 3/EU).
//
// r15 theory: issue-bound at the step-window level (VALUBusy 67% ~= 2260cy
// of a 3371cy window). Two per-step chunks are computed IDENTICALLY in all
// 4 waves (same zf, same weights, same x):
//   1. readout (4 MFMA + ~100cy VALU) -> only wave des = blockIdx.x & 3
//      (designation rotates across blocks -> spreads across SIMDs).
//   2. encoder spikes = pure function of x -> precompute all 40 ballot
//      masks in prologue (wave des), 640B in LDS; steady loop reads 16B
//      uniform per step. Frees cur/ve regs.
// Values bit-identical to r11 (same ops, same order) -> absmax 0.001953125.
// Guard: WRITE_SIZE == 512 KB (spill tripwire), VGPR <= 80.

#pragma clang fp contract(off)

typedef float f32x4 __attribute__((ext_vector_type(4)));
typedef float f32x2 __attribute__((ext_vector_type(2)));
typedef short short8 __attribute__((ext_vector_type(8)));
typedef int int4v __attribute__((ext_vector_type(4)));

constexpr int TSTEPS = 40;

// round-to-nearest-even bf16, returned as f32 bit pattern (low 16 zero)
__device__ __forceinline__ unsigned rnbf(float f) {
    unsigned u = __float_as_uint(f);
    return (u + 0x7FFFu + ((u >> 16) & 1u)) & 0xFFFF0000u;
}

// 2-way RN split of an f32 pair into packed bf16 (lo16 = even-k element)
__device__ __forceinline__ void split2pair(float a, float b,
                                           unsigned& hi, unsigned& mi) {
    unsigned ha = rnbf(a), hb = rnbf(b);
    float ra = a - __uint_as_float(ha);
    float rb = b - __uint_as_float(hb);
    unsigned ma = rnbf(ra), mb = rnbf(rb);
    hi = (ha >> 16) | (hb & 0xFFFF0000u);
    mi = (ma >> 16) | (mb & 0xFFFF0000u);
}

__device__ __forceinline__ f32x4 mfma16(int4v a, int4v b, f32x4 c) {
    return __builtin_amdgcn_mfma_f32_16x16x32_bf16(
        __builtin_bit_cast(short8, a), __builtin_bit_cast(short8, b), c, 0, 0, 0);
}

template <int CTRL>
__device__ __forceinline__ float dpp_mov(float v) {
    return __int_as_float(
        __builtin_amdgcn_update_dpp(0, __float_as_int(v), CTRL, 0xF, 0xF, true));
}

__device__ __forceinline__ f32x2 lo2(f32x4 a) {
    return __builtin_shufflevector(a, a, 0, 1);
}
__device__ __forceinline__ f32x2 hi2(f32x4 a) {
    return __builtin_shufflevector(a, a, 2, 3);
}

__global__ __launch_bounds__(256, 3) void snn_kernel(
    const float* __restrict__ x,
    const float* __restrict__ w_in,
    const float* __restrict__ w_rec,
    const float* __restrict__ w_out,
    float* __restrict__ out)
{
    __shared__ char zraw[8192];     // 2 x (16 rows x 128 cols bf16), swizzled
    __shared__ __align__(16) unsigned long long msk[TSTEPS][2];  // spike masks

    const int tid = threadIdx.x;
    const int l   = tid & 63;
    const int wv  = tid >> 6;      // wave 0..3
    const int cl  = l & 15;        // row (A/write col-lane) / col (B/C)
    const int kg  = l >> 4;        // k-group 0..3
    const int kb  = kg * 8;        // k base within a 32-chunk
    const int b0  = blockIdx.x * 16;
    const int Ns  = wv * 32;       // neuron slice base
    const int des = blockIdx.x & 3; // designated readout/encoder wave

    // packed-op constants
    const f32x2 P1  = {0.1f, 0.1f};
    const f32x2 P02 = {0.2f, 0.2f};

    // ---- recurrent weights: BOTH splits -> registers (r11 layout)
    int4v BrecHi[2][4], BrecMi[2][4];
#pragma unroll
    for (int t = 0; t < 2; ++t) {
        int n = Ns + t * 16 + cl;
#pragma unroll
        for (int kc = 0; kc < 4; ++kc) {
            const float* wp = w_rec + n * 128 + kc * 32 + kb;
            float4 wa = *reinterpret_cast<const float4*>(wp);
            float4 wb = *reinterpret_cast<const float4*>(wp + 4);
            float w8[8] = {wa.x, wa.y, wa.z, wa.w, wb.x, wb.y, wb.z, wb.w};
#pragma unroll
            for (int r = 0; r < 4; ++r) {
                unsigned h, m;
                split2pair(w8[2 * r], w8[2 * r + 1], h, m);
                BrecHi[t][kc][r] = (int)h;
                BrecMi[t][kc][r] = (int)m;
            }
        }
    }

    // ---- input weights, hi+mid PACKED in one B-frag (kg0=hi, kg1=mid)
    int4v BwinPk[2];
#pragma unroll
    for (int t = 0; t < 2; ++t) {
        int n = Ns + t * 16 + cl;
        float w8[8];
#pragma unroll
        for (int j = 0; j < 8; ++j)
            w8[j] = (kg < 2) ? w_in[n * 8 + j] : 0.0f;
#pragma unroll
        for (int r = 0; r < 4; ++r) {
            unsigned h, m;
            split2pair(w8[2 * r], w8[2 * r + 1], h, m);
            BwinPk[t][r] = (int)(kg == 0 ? h : (kg == 1 ? m : 0u));
        }
    }

    // ---- readout weights: cols 0,1 = hi(ch0),hi(ch1); cols 2,3 = mid
    int4v Bwout[4];
    {
        int  ch   = cl & 1;
        int  part = (cl >> 1) & 1;
        bool act  = cl < 4;
#pragma unroll
        for (int kc = 0; kc < 4; ++kc) {
            float w8[8];
#pragma unroll
            for (int j = 0; j < 8; ++j)
                w8[j] = act ? w_out[ch * 128 + kc * 32 + kb + j] : 0.0f;
#pragma unroll
            for (int r = 0; r < 4; ++r) {
                unsigned h, m;
                split2pair(w8[2 * r], w8[2 * r + 1], h, m);
                Bwout[kc][r] = (int)(part ? m : h);
            }
        }
    }

    // ---- encoder: PRECOMPUTE all 40 spike masks (pure function of x).
    // Same op chain as r11's per-step encoder, just hoisted. Wave des only.
    if (wv == des) {
        float xv0 = x[(size_t)(b0 + (l >> 3)) * 4 + (l & 3)];
        float xv1 = x[(size_t)(b0 + 8 + (l >> 3)) * 4 + (l & 3)];
        float s0 = 50.0f * xv0, s1 = 50.0f * xv1;
        f32x2 cur, ve = {0.0f, 0.0f};
        cur[0] = (l & 4) ? fmaxf(-s0, 0.0f) : fmaxf(s0, 0.0f);
        cur[1] = (l & 4) ? fmaxf(-s1, 0.0f) : fmaxf(s1, 0.0f);
#pragma unroll 1
        for (int u = 0; u < TSTEPS; ++u) {
            f32x2 te = cur - ve;            // (0-ve)+cur == cur-ve
            f32x2 vv = ve + P1 * te;
            bool e0 = vv[0] > 1.0f, e1 = vv[1] > 1.0f;
            unsigned long long bm0 = __ballot(e0), bm1 = __ballot(e1);
            ve[0] = e0 ? 0.0f : vv[0];
            ve[1] = e1 ? 0.0f : vv[1];
            if (l == 0) { msk[u][0] = bm0; msk[u][1] = bm1; }
        }
    }

    // ---- states (C-frag layout: col=lane&15, row=(lane>>4)*4+reg)
    f32x2 iSl[2] = {{0,0},{0,0}}, iSh[2] = {{0,0},{0,0}};
    f32x2 vSl[2] = {{0,0},{0,0}}, vSh[2] = {{0,0},{0,0}};
    f32x2 io_l = {0,0}, io_h = {0,0}, vo_l = {0,0}, vo_h = {0,0};
    f32x4 mx = {-3e38f,-3e38f,-3e38f,-3e38f};

    // ---- z-tile LDS addresses (byte ^ ((row&7)<<4) swizzle; bit12 = buffer)
    unsigned awrb[2];
#pragma unroll
    for (int t = 0; t < 2; ++t) {
        int col = Ns + t * 16 + cl;
        awrb[t] = (unsigned)((kg * 1024 + col * 2) ^ ((kg & 1) << 6));
    }
    unsigned ard = (unsigned)((cl * 256 + kg * 16) ^ ((cl & 7) << 4)) | 4096u;

    auto loadfrags = [&](int4v* zf) {
#pragma unroll
        for (int kc = 0; kc < 4; ++kc)
            zf[kc] = *reinterpret_cast<int4v*>(&zraw[ard ^ (unsigned)(kc << 6)]);
    };

    auto readout = [&](const int4v* zf) {
        f32x4 cro = {0,0,0,0};
#pragma unroll
        for (int kc = 0; kc < 4; ++kc) cro = mfma16(zf[kc], Bwout[kc], cro);
        f32x4 cr;
#pragma unroll
        for (int r = 0; r < 4; ++r) cr[r] = cro[r] + dpp_mov<0x4E>(cro[r]);
        // von = vo + 0.1*((0 - vo) + io); (0-vo)+io == io - vo (one rounding)
        f32x2 t2l = io_l - vo_l;
        f32x2 t2h = io_h - vo_h;
        f32x2 vnl = vo_l + P1 * t2l;
        f32x2 vnh = vo_h + P1 * t2h;
        // io = (io - 0.2*io) + cr   (vo used OLD io above)
        io_l = (io_l - P02 * io_l) + lo2(cr);
        io_h = (io_h - P02 * io_h) + hi2(cr);
        vo_l = vnl;
        vo_h = vnh;
        mx[0] = fmaxf(mx[0], vnl[0]);
        mx[1] = fmaxf(mx[1], vnl[1]);
        mx[2] = fmaxf(mx[2], vnh[0]);
        mx[3] = fmaxf(mx[3], vnh[1]);
    };

    auto encoder_lif = [&](int u, bool with_rec, const int4v* zf) {
        // spike byte from precomputed masks (uniform LDS read)
        unsigned long long bm0 = msk[u][0];
        unsigned long long bm1 = msk[u][1];
        unsigned long long src = (cl < 8) ? (bm0 >> (cl * 8)) : (bm1 >> ((cl - 8) * 8));
        unsigned byt = (l < 32) ? ((unsigned)src & 0xFFu) : 0u;
        int4v axt;
        axt[0] = (int)(((byt & 1u)   ? 0x3F80u : 0u) | ((byt & 2u)   ? 0x3F800000u : 0u));
        axt[1] = (int)(((byt & 4u)   ? 0x3F80u : 0u) | ((byt & 8u)   ? 0x3F800000u : 0u));
        axt[2] = (int)(((byt & 16u)  ? 0x3F80u : 0u) | ((byt & 32u)  ? 0x3F800000u : 0u));
        axt[3] = (int)(((byt & 64u)  ? 0x3F80u : 0u) | ((byt & 128u) ? 0x3F800000u : 0u));
#pragma unroll
        for (int t = 0; t < 2; ++t) {
            f32x2 idl, idh, ttl, tth, vdl, vdh;
            f32x4 cin = {0,0,0,0};
            cin = mfma16(axt, BwinPk[t], cin);   // hi + mid in one pass
            f32x4 crec = {0,0,0,0};
            if (with_rec) {
#pragma unroll
                for (int kc = 0; kc < 4; ++kc)
                    crec = mfma16(zf[kc], BrecMi[t][kc], crec);
#pragma unroll
                for (int kc = 0; kc < 4; ++kc)
                    crec = mfma16(zf[kc], BrecHi[t][kc], crec);
            }
            // id = i - 0.2*i ; tt = (0-v)+i == i-v ; vd = v + 0.1*tt
            idl = iSl[t] - P02 * iSl[t];
            idh = iSh[t] - P02 * iSh[t];
            ttl = iSl[t] - vSl[t];
            tth = iSh[t] - vSh[t];
            vdl = vSl[t] + P1 * ttl;
            vdh = vSh[t] + P1 * tth;
#pragma unroll
            for (int r = 0; r < 4; ++r) {
                float vdr = (r < 2) ? vdl[r] : vdh[r - 2];
                bool zb = vdr > 1.0f;
                float vres = zb ? 0.0f : vdr;
                if (r == 0)      vSl[t][0] = vres;
                else if (r == 1) vSl[t][1] = vres;
                else if (r == 2) vSh[t][0] = vres;
                else             vSh[t][1] = vres;
                short zv = zb ? (short)0x3F80 : (short)0;
                unsigned a = (awrb[t] ^ (unsigned)(r << 4)) + (unsigned)(r * 256);
                *reinterpret_cast<short*>(&zraw[a]) = zv;
            }
            // iS = (id + cin) + crec    [r11 order]
            iSl[t] = (idl + lo2(cin)) + lo2(crec);
            iSh[t] = (idh + hi2(cin)) + hi2(crec);
        }
    };

    auto toggle = [&]() {
        ard ^= 4096u;
        awrb[0] ^= 4096u;
        awrb[1] ^= 4096u;
    };

    // ---- prologue: masks visible -> z(0) written -> z(0) visible
    __syncthreads();
    encoder_lif(0, false, nullptr);
    __syncthreads();
    toggle();

#pragma unroll 1
    for (int u = 1; u < TSTEPS; ++u) {
        int4v zf[4];
        loadfrags(zf);                     // z(u-1)
        if (wv == des) readout(zf);        // vo(u-1), io(u-1): one wave only
        encoder_lif(u, true, zf);          // i/v/z(u)
        __syncthreads();
        toggle();
    }

    // ---- epilogue: vo(39) from z(39); softmax + store (designated wave)
    if (wv == des) {
        int4v zf[4];
        loadfrags(zf);
        readout(zf);
#pragma unroll
        for (int r = 0; r < 4; ++r) {
            float partner = dpp_mov<0xB1>(mx[r]);
            float mm = fmaxf(mx[r], partner);
            float es = expf(mx[r] - mm);
            float ep = expf(partner - mm);
            float inv = 1.0f / (es + ep);
            float pr = es * inv;
            if (cl < 2) out[(size_t)(b0 + kg * 4 + r) * 2 + cl] = pr;
        }
    }
}

extern "C" void kernel_launch(void* const* d_in, const int* in_sizes, int n_in,
                              void* d_out, int out_size, void* d_ws, size_t ws_size,
                              hipStream_t stream) {
    const float* x     = (const float*)d_in[0];
    const float* w_in  = (const float*)d_in[1];
    const float* w_rec = (const float*)d_in[2];
    const float* w_out = (const float*)d_in[3];
    float* out = (float*)d_out;

    int B = in_sizes[0] / 4;      // x is (B, 4)
    int blocks = B / 16;          // 16 batch elements per 256-thread block
    snn_kernel<<<blocks, 256, 0, stream>>>(x, w_in, w_rec, w_out, out);
}